// Round 8
// baseline (147.139 us; speedup 1.0000x reference)
//
#include <hip/hip_runtime.h>

#define H 512
#define WID 1024
#define HW (H*WID)
#define B 4
#define K 8
#define NB 1024
#define NBLK1 128                          // k1 blocks per image

// ws word (4-byte) layout
#define OFF_LOSS  0
#define OFF_TICK  1                        // out-write ticket (u32)
#define OFF_TICK2 2                        // 32 per-bk chunk tickets (u32)
#define OFF_FIN   64                       // B*K*8 floats: only [+4]=cnt used
#define OFF_SPART 512                      // B*K*NBLK1*8 floats (stride 8)
#define OFF_RED   (OFF_SPART + B*K*NBLK1*8)   // 2*B*K*NB u32 (cnt then pos)
#define OFF_PART  (OFF_RED + 2*B*K*NB)     // B*G*K*NB packed u32 (pos<<16|cnt)

static __device__ __forceinline__ float frcp(float x){
#if __has_builtin(__builtin_amdgcn_rcpf)
  return __builtin_amdgcn_rcpf(x);
#else
  return 1.0f / x;
#endif
}
static __device__ __forceinline__ float fexp2(float x){
#if __has_builtin(__builtin_amdgcn_exp2f)
  return __builtin_amdgcn_exp2f(x);
#else
  return exp2f(x);
#endif
}
static __device__ __forceinline__ float ftanh(float x){
  return 1.0f - 2.0f * frcp(__expf(2.0f*x) + 1.0f);
}
static __device__ __forceinline__ float fsigmoid(float x){
  return frcp(1.0f + __expf(-x));
}

// ---------------- Kernel 1: per-(b,k) stats + zero LOSS/TICK/tickets/red ----------------
__global__ __launch_bounds__(512) void k1_stats(const float* __restrict__ pred,
                                                const int* __restrict__ inst,
                                                float* __restrict__ ws,
                                                unsigned int* __restrict__ red) {
  const int b = blockIdx.y;
  __shared__ int4   ti[1024];
  __shared__ float4 ts[1024];
  __shared__ float  part5[K][5];
  {
    const int blin = b*NBLK1 + blockIdx.x;          // 0..511
    if (threadIdx.x < 32)                            // zero 128 u32 of red per block
      ((uint4*)red)[(size_t)blin*32 + threadIdx.x] = make_uint4(0u,0u,0u,0u);
    if (blin == 0 && threadIdx.x >= 32 && threadIdx.x < 66)
      ((unsigned int*)ws)[threadIdx.x - 32] = 0u;    // words 0..33: LOSS,TICK,TICK2[32]
  }
  const float4* sig4 = (const float4*)(pred + (size_t)(8*b + 5) * HW);  // ch2 t=1
  const int4*   ins4 = (const int4*)(inst + (size_t)(2*b + 1) * HW);
  const int base4 = blockIdx.x * 1024;     // 1024 int4-groups per block
  #pragma unroll
  for (int i = 0; i < 2; i++) {
    const int q = threadIdx.x + i*512;
    ti[q] = ins4[base4 + q];
    ts[q] = sig4[base4 + q];
  }
  __syncthreads();
  const int wv = threadIdx.x >> 6, lane = threadIdx.x & 63;
  const int kk = wv + 1;
  float cnt=0.f, sx=0.f, sy=0.f, ss=0.f, ss2=0.f;
  #pragma unroll
  for (int j = 0; j < 16; j++) {
    const int q = lane + 64*j;
    const int4   iv = ti[q];
    const float4 sv = ts[q];
    const int p = (base4 + q) * 4;
    const float xm0 = (float)(p & (WID-1)) * (2.0f/2047.0f);
    const float ym  = (float)(p >> 10)     * (1.0f/1023.0f);
    const float m0 = (iv.x==kk)?1.f:0.f, m1=(iv.y==kk)?1.f:0.f,
                m2 = (iv.z==kk)?1.f:0.f, m3=(iv.w==kk)?1.f:0.f;
    const float msum = (m0+m1)+(m2+m3);
    cnt += msum;
    sx  += msum*xm0 + (m1 + 2.0f*m2 + 3.0f*m3)*(2.0f/2047.0f);
    sy  += msum*ym;
    ss  += m0*sv.x + m1*sv.y + m2*sv.z + m3*sv.w;
    ss2 += m0*sv.x*sv.x + m1*sv.y*sv.y + m2*sv.z*sv.z + m3*sv.w*sv.w;
  }
  #pragma unroll
  for (int o=1;o<64;o<<=1){
    cnt+=__shfl_xor(cnt,o,64);
    sx +=__shfl_xor(sx, o,64);
    sy +=__shfl_xor(sy, o,64);
    ss +=__shfl_xor(ss, o,64);
    ss2+=__shfl_xor(ss2,o,64);
  }
  if (lane == 0) {
    part5[wv][0]=cnt; part5[wv][1]=sx; part5[wv][2]=sy; part5[wv][3]=ss; part5[wv][4]=ss2;
  }
  __syncthreads();
  if (threadIdx.x < K*8) {
    const int w = threadIdx.x >> 3, c = threadIdx.x & 7;
    if (c < 5)
      ws[OFF_SPART + ((size_t)(b*K + w)*NBLK1 + blockIdx.x)*8 + c] = part5[w][c];
  }
}

// ---------------- Kernel 3: main pass (k2 fused) — round-3 proven body ----------------
// 1024 thr (16 waves), G=128 -> 2 blocks/CU = 32 waves/CU. LDS hist flushed as
// plain coalesced uint4 stores to the part slab (bulk device atomics cost ~15 µs
// more — round 6; do NOT reintroduce).
template<int G>
__global__ __launch_bounds__(1024, 8) void k3_main(const float* __restrict__ pred,
                                                   const int* __restrict__ inst,
                                                   float* __restrict__ ws,
                                                   unsigned int* __restrict__ part) {
  const int b = blockIdx.y, g = blockIdx.x;
  __shared__ unsigned int hist[K*NB];           // pos<<16 | cnt, 32 KiB
  __shared__ float4 finL[K];
  __shared__ float  vlocL[K];
  for (int i = threadIdx.x*4; i < K*NB; i += 1024*4)
    *(uint4*)&hist[i] = make_uint4(0u,0u,0u,0u);
  const int wv = threadIdx.x >> 6, lane = threadIdx.x & 63;
  // ---- fused k2: wave wv (0..7) reduces spart for k=wv ----
  if (wv < K) {
    const float* p = ws + OFF_SPART + (size_t)(b*K + wv)*NBLK1*8;
    const float4 q0 = *(const float4*)(p + (size_t)lane*8);
    const float  e0 = p[(size_t)lane*8 + 4];
    const float4 q1 = *(const float4*)(p + (size_t)(lane+64)*8);
    const float  e1 = p[(size_t)(lane+64)*8 + 4];
    float a0=q0.x+q1.x, a1=q0.y+q1.y, a2=q0.z+q1.z, a3=q0.w+q1.w, a4=e0+e1;
    #pragma unroll
    for (int o=1;o<64;o<<=1){
      a0+=__shfl_xor(a0,o,64); a1+=__shfl_xor(a1,o,64); a2+=__shfl_xor(a2,o,64);
      a3+=__shfl_xor(a3,o,64); a4+=__shfl_xor(a4,o,64);
    }
    if (lane == 0) {
      const float cnt=a0, sx=a1, sy=a2, ss=a3, ss2=a4;
      const float present = (cnt > 0.0f) ? 1.0f : 0.0f;
      const float safe = fmaxf(cnt, 1.0f);
      const float cx = sx/safe, cy = sy/safe, sm = ss/safe;
      const float var = (ss2 - 2.0f*sm*ss + sm*sm*cnt)/safe;   // N_SIGMA=1
      const float sexp = expf(10.0f * sm);
      const float L2E = 1.4426950408889634f;
      finL[wv] = make_float4(-sexp*L2E,                        // a
                              2.0f*sexp*cx*L2E,                // bx
                              2.0f*sexp*cy*L2E,                // by
                             -sexp*(cx*cx + cy*cy)*L2E + 10.0f); // d0 (+10 = x1024 scale)
      vlocL[wv] = present * 10.0f * var * (1.0f/3.0f);         // W_VAR=10, /(B-1)
      if (g == 0) ws[OFF_FIN + (b*K + wv)*8 + 4] = cnt;        // for k4
    }
  }
  __syncthreads();
  float4 fr[K];
  #pragma unroll
  for (int k=0;k<K;k++) fr[k] = finL[k];      // broadcast reads
  const float4* p0 = (const float4*)(pred + (size_t)(8*b+1)*HW);
  const float4* p1 = (const float4*)(pred + (size_t)(8*b+3)*HW);
  const float4* p3 = (const float4*)(pred + (size_t)(8*b+7)*HW);
  const int4*   in4 = (const int4*)(inst + (size_t)(2*b+1)*HW);
  float sAcc = 0.0f;
  constexpr int CH4 = HW / (G*4);
  const int base4 = g * CH4;
  for (int q0 = 0; q0 < CH4; q0 += 1024) {
    const int idx = base4 + q0 + threadIdx.x;
    const int4   iv = in4[idx];
    const float4 f0 = p0[idx];
    const float4 f1 = p1[idx];
    const float4 f3 = p3[idx];
    const int p = idx * 4;
    const float xm0 = (float)(p & (WID-1)) * (2.0f/2047.0f);
    const float ym  = (float)(p >> 10)     * (1.0f/1023.0f);
    const int ivv[4] = {iv.x, iv.y, iv.z, iv.w};
    float pxv[4], pyv[4], t2v[4], down[4];
    {
      const float a0v[4] = {f0.x, f0.y, f0.z, f0.w};
      const float a1v[4] = {f1.x, f1.y, f1.z, f1.w};
      #pragma unroll
      for (int e=0;e<4;e++){
        pxv[e] = ftanh(a0v[e]) + xm0 + (float)e*(2.0f/2047.0f);
        pyv[e] = ftanh(a1v[e]) + ym;
        t2v[e] = pxv[e]*pxv[e] + pyv[e]*pyv[e];
        down[e] = 0.0f;
      }
    }
    #pragma unroll
    for (int j=0;j<K;j++){
      const float4 f = fr[j];
      int buv[4]; unsigned addv[4];
      #pragma unroll
      for (int e=0;e<4;e++){
        const float u = fmaf(f.x, t2v[e], fmaf(f.y, pxv[e], fmaf(f.z, pyv[e], f.w)));
        const float v = fexp2(u);                 // 1024*dist in [0,1024]
        int vi = (int)v; vi = (vi > NB-1) ? NB-1 : vi;
        const bool own = (ivv[e] == j+1);
        if (own) down[e] = v;
        buv[e] = own ? (NB-1 - vi) : vi;
        addv[e] = own ? 0x10001u : 1u;
      }
      // merge runs of equal buckets within the quad
      int cur = buv[0]; unsigned acc = addv[0];
      #pragma unroll
      for (int e=1;e<4;e++){
        const bool same = (buv[e] == cur);
        if (!same) atomicAdd(&hist[j*NB + cur], acc);
        acc = same ? acc + addv[e] : addv[e];
        cur = buv[e];
      }
      atomicAdd(&hist[j*NB + cur], acc);
    }
    {
      const float sdv[4] = {fsigmoid(f3.x), fsigmoid(f3.y), fsigmoid(f3.z), fsigmoid(f3.w)};
      #pragma unroll
      for (int e=0;e<4;e++){
        const float d  = (ivv[e] == 0) ? 0.0f : down[e] * (1.0f/1024.0f);
        const float df = sdv[e] - d;
        sAcc += df*df;                            // bg: sd^2; fg: (sd-dist)^2
      }
    }
  }
  __syncthreads();
  unsigned int* dst = part + ((size_t)b*G + g)*(K*NB);
  for (int i = threadIdx.x*4; i < K*NB; i += 1024*4)
    *(uint4*)&dst[i] = *(const uint4*)&hist[i];
  #pragma unroll
  for (int o=1;o<64;o<<=1) sAcc += __shfl_xor(sAcc, o, 64);
  __shared__ float wsum[16];
  if (lane == 0) wsum[wv] = sAcc;
  __syncthreads();
  if (threadIdx.x == 0) {
    float tot = 0.f;
    #pragma unroll
    for (int w = 0; w < 16; w++) tot += wsum[w];
    float add = tot * (1.0f/((float)HW * 3.0f));  // W_SEED /npix /(B-1)
    if (g == 0) {
      #pragma unroll
      for (int k = 0; k < K; k++) add += vlocL[k];  // var loss, once per image
    }
    atomicAdd(ws + OFF_LOSS, add);
  }
}

// ---------------- Kernel 4: parallel G-reduction + last-block Lovász + output ----------------
// 256 blocks x 1024 thr. Block (bk, chunk): reduces 128 buckets x G slabs
// (65 KB/block, coalesced) -> device-atomicAdd into pre-zeroed red (coherent,
// no fence subtleties for the data). 8th chunk-block per bk (ticket) runs the
// 1-bucket/thread Lovász scan from red. Fixes round-7's 32-block serialization
// (512 KB through one CU's pipe ≈ 21 µs) while keeping a single dispatch.
__global__ __launch_bounds__(1024) void k4_red(const unsigned int* __restrict__ part,
                                               float* __restrict__ ws,
                                               unsigned int* __restrict__ red,
                                               float* __restrict__ out, int G_) {
  const int bid = blockIdx.x;
  const int bk = bid >> 3, chunk = bid & 7;
  const int b = bk >> 3, k = bk & 7;
  const int t = threadIdx.x, lane = t & 63, wv = t >> 6;
  __shared__ unsigned int cnt2[1024], pos2[1024];
  __shared__ int    wtc[16], wtp[16];
  __shared__ double racc[16];
  __shared__ unsigned int lastFlag;
  {
    const int gg = t >> 7, bl = t & 127;        // 8 g-groups x 128 buckets
    const int bu = chunk*128 + bl;
    unsigned rc = 0, rp = 0;
    #pragma unroll 4
    for (int g = gg; g < G_; g += 8) {
      const unsigned v = part[((size_t)(b*G_ + g)*K + k)*NB + bu];
      rc += v & 0xFFFFu;
      rp += v >> 16;
    }
    cnt2[t] = rc; pos2[t] = rp;
  }
  __syncthreads();
  if (t < 128) {
    unsigned c = 0, p = 0;
    #pragma unroll
    for (int q = 0; q < 8; q++) { c += cnt2[q*128 + t]; p += pos2[q*128 + t]; }
    const int bu = chunk*128 + t;
    if (c) atomicAdd(&red[(size_t)bk*NB + bu], c);           // red pre-zeroed by k1
    if (p) atomicAdd(&red[(size_t)B*K*NB + bk*NB + bu], p);
  }
  __syncthreads();                     // drains this block's atomics (vmcnt(0))
  if (t == 0) {
    __threadfence();
    lastFlag = atomicAdd(&((unsigned int*)ws)[OFF_TICK2 + bk], 1u);
  }
  __syncthreads();
  if (lastFlag != 7u) return;          // only the last chunk-block finalizes
  __threadfence();                     // acquire: see other blocks' red atomics
  const float cntF = ws[OFF_FIN + bk*8 + 4];
  if (cntF > 0.0f) {
    const double Pd = (double)cntF;
    const int bu = NB-1 - t;                    // descending error order
    const unsigned rc = red[(size_t)bk*NB + bu];
    const unsigned rp = red[(size_t)B*K*NB + bk*NB + bu];
    int ic = (int)rc, ip = (int)rp;
    #pragma unroll
    for (int o=1;o<64;o<<=1){
      const int vc = __shfl_up(ic, o, 64);
      const int vp = __shfl_up(ip, o, 64);
      if (lane >= o) { ic += vc; ip += vp; }
    }
    if (lane == 63) { wtc[wv] = ic; wtp[wv] = ip; }
    __syncthreads();
    int offc = 0, offp = 0;
    for (int w = 0; w < wv; w++) { offc += wtc[w]; offp += wtp[w]; }
    const int irun = offc + ic - (int)rc;       // exclusive prefixes
    const int crun = offp + ip - (int)rp;
    double acc = 0.0;
    if (rc) {
      const double jac0 = (irun==0) ? 0.0 : 1.0 - (Pd - crun)/(Pd + irun - crun);
      const int ir1 = irun + (int)rc, cr1 = crun + (int)rp;
      const double jac1 = 1.0 - (Pd - cr1)/(Pd + ir1 - cr1);
      acc = ((bu + 0.5) * (2.0/NB)) * (jac1 - jac0);
    }
    #pragma unroll
    for (int o=1;o<64;o<<=1) acc += __shfl_xor(acc, o, 64);
    if (lane == 0) racc[wv] = acc;
    __syncthreads();
    if (t == 0) {
      double tot = 0.0;
      #pragma unroll
      for (int w = 0; w < 16; w++) tot += racc[w];
      atomicAdd(ws + OFF_LOSS, (float)(tot * (1.0/3.0)));   // W_INST=1, /(B-1)
    }
  }
  // completion ticket: last finalizer writes the output
  if (t == 0) {
    __threadfence();
    unsigned int* wsu = (unsigned int*)ws;
    const unsigned int old = atomicAdd(&wsu[OFF_TICK], 1u);
    if (old == (unsigned)(B*K - 1)) {
      __threadfence();
      out[0] = *((volatile float*)(ws + OFF_LOSS));
    }
  }
}

extern "C" void kernel_launch(void* const* d_in, const int* in_sizes, int n_in,
                              void* d_out, int out_size, void* d_ws, size_t ws_size,
                              hipStream_t stream) {
  const float* pred = (const float*)d_in[0];
  const int*   inst = (const int*)d_in[1];
  float* ws  = (float*)d_ws;
  float* out = (float*)d_out;
  unsigned int* red  = ((unsigned int*)d_ws) + OFF_RED;
  unsigned int* part = ((unsigned int*)d_ws) + OFF_PART;
  int G = 128;
  while (G > 32 && ws_size < ((size_t)OFF_PART + (size_t)B*G*K*NB)*4) G >>= 1;
  k1_stats<<<dim3(NBLK1,B), 512, 0, stream>>>(pred, inst, ws, red);
  if      (G == 128) k3_main<128><<<dim3(128,B), 1024, 0, stream>>>(pred, inst, ws, part);
  else if (G ==  64) k3_main< 64><<<dim3( 64,B), 1024, 0, stream>>>(pred, inst, ws, part);
  else               k3_main< 32><<<dim3( 32,B), 1024, 0, stream>>>(pred, inst, ws, part);
  k4_red<<<B*K*8, 1024, 0, stream>>>(part, ws, red, out, G);
}

// Round 9
// 134.669 us; speedup vs baseline: 1.0926x; 1.0926x over previous
//
#include <hip/hip_runtime.h>

#define H 512
#define WID 1024
#define HW (H*WID)
#define B 4
#define K 8
#define NB 1024
#define NBLK1 128                          // k1 blocks per image

// ws word (4-byte) layout
#define OFF_LOSS  0
#define OFF_TICK  1                        // out-write ticket (u32)
#define OFF_FIN   64                       // B*K*8 floats: only [+4]=cnt used
#define OFF_SPART 512                      // B*K*NBLK1*8 floats (stride 8)
#define OFF_RED   (OFF_SPART + B*K*NBLK1*8)   // 2*B*K*NB u32 (cnt then pos)
#define OFF_PART  (OFF_RED + 2*B*K*NB)     // B*G*K*NB packed u32 (pos<<16|cnt)

static __device__ __forceinline__ float frcp(float x){
#if __has_builtin(__builtin_amdgcn_rcpf)
  return __builtin_amdgcn_rcpf(x);
#else
  return 1.0f / x;
#endif
}
static __device__ __forceinline__ float fexp2(float x){
#if __has_builtin(__builtin_amdgcn_exp2f)
  return __builtin_amdgcn_exp2f(x);
#else
  return exp2f(x);
#endif
}
static __device__ __forceinline__ float ftanh(float x){
  return 1.0f - 2.0f * frcp(__expf(2.0f*x) + 1.0f);
}
static __device__ __forceinline__ float fsigmoid(float x){
  return frcp(1.0f + __expf(-x));
}
// DPP lane-xor within 4-lane quads: VALU-only (no LDS pipe), unlike __shfl.
static __device__ __forceinline__ int dpp_xor1_i(int x){
#if __has_builtin(__builtin_amdgcn_mov_dpp)
  return __builtin_amdgcn_mov_dpp(x, 0xB1, 0xF, 0xF, true);   // quad_perm [1,0,3,2]
#else
  return __shfl_xor(x, 1, 64);
#endif
}
static __device__ __forceinline__ int dpp_xor2_i(int x){
#if __has_builtin(__builtin_amdgcn_mov_dpp)
  return __builtin_amdgcn_mov_dpp(x, 0x4E, 0xF, 0xF, true);   // quad_perm [2,3,0,1]
#else
  return __shfl_xor(x, 2, 64);
#endif
}

// ---------------- Kernel 1: per-(b,k) stats + zero LOSS/TICK ----------------
__global__ __launch_bounds__(512) void k1_stats(const float* __restrict__ pred,
                                                const int* __restrict__ inst,
                                                float* __restrict__ ws) {
  const int b = blockIdx.y;
  __shared__ int4   ti[1024];
  __shared__ float4 ts[1024];
  __shared__ float  part5[K][5];
  if (b == 0 && blockIdx.x == 0) {
    if (threadIdx.x == 0) ws[OFF_LOSS] = 0.0f;
    if (threadIdx.x == 1) ((unsigned int*)ws)[OFF_TICK] = 0u;
  }
  const float4* sig4 = (const float4*)(pred + (size_t)(8*b + 5) * HW);  // ch2 t=1
  const int4*   ins4 = (const int4*)(inst + (size_t)(2*b + 1) * HW);
  const int base4 = blockIdx.x * 1024;     // 1024 int4-groups per block
  #pragma unroll
  for (int i = 0; i < 2; i++) {
    const int q = threadIdx.x + i*512;
    ti[q] = ins4[base4 + q];
    ts[q] = sig4[base4 + q];
  }
  __syncthreads();
  const int wv = threadIdx.x >> 6, lane = threadIdx.x & 63;
  const int kk = wv + 1;
  float cnt=0.f, sx=0.f, sy=0.f, ss=0.f, ss2=0.f;
  #pragma unroll
  for (int j = 0; j < 16; j++) {
    const int q = lane + 64*j;
    const int4   iv = ti[q];
    const float4 sv = ts[q];
    const int p = (base4 + q) * 4;
    const float xm0 = (float)(p & (WID-1)) * (2.0f/2047.0f);
    const float ym  = (float)(p >> 10)     * (1.0f/1023.0f);
    const float m0 = (iv.x==kk)?1.f:0.f, m1=(iv.y==kk)?1.f:0.f,
                m2 = (iv.z==kk)?1.f:0.f, m3=(iv.w==kk)?1.f:0.f;
    const float msum = (m0+m1)+(m2+m3);
    cnt += msum;
    sx  += msum*xm0 + (m1 + 2.0f*m2 + 3.0f*m3)*(2.0f/2047.0f);
    sy  += msum*ym;
    ss  += m0*sv.x + m1*sv.y + m2*sv.z + m3*sv.w;
    ss2 += m0*sv.x*sv.x + m1*sv.y*sv.y + m2*sv.z*sv.z + m3*sv.w*sv.w;
  }
  #pragma unroll
  for (int o=1;o<64;o<<=1){
    cnt+=__shfl_xor(cnt,o,64);
    sx +=__shfl_xor(sx, o,64);
    sy +=__shfl_xor(sy, o,64);
    ss +=__shfl_xor(ss, o,64);
    ss2+=__shfl_xor(ss2,o,64);
  }
  if (lane == 0) {
    part5[wv][0]=cnt; part5[wv][1]=sx; part5[wv][2]=sy; part5[wv][3]=ss; part5[wv][4]=ss2;
  }
  __syncthreads();
  if (threadIdx.x < K*8) {
    const int w = threadIdx.x >> 3, c = threadIdx.x & 7;
    if (c < 5)
      ws[OFF_SPART + ((size_t)(b*K + w)*NBLK1 + blockIdx.x)*8 + c] = part5[w][c];
  }
}

// ---------------- Kernel 3: main pass (k2 fused) — + DPP cross-lane atomic merge ----------------
// 1024 thr (16 waves), G=128 -> 2 blocks/CU = 32 waves/CU. LDS hist flushed as
// plain coalesced uint4 stores (cross-block atomics/tickets cost 15-25 µs —
// rounds 6/7/8; do NOT reintroduce). New: equal-bucket lanes within each
// 4-lane quad merge their ds_add via DPP (VALU-only) before hitting LDS.
template<int G>
__global__ __launch_bounds__(1024, 8) void k3_main(const float* __restrict__ pred,
                                                   const int* __restrict__ inst,
                                                   float* __restrict__ ws,
                                                   unsigned int* __restrict__ part) {
  const int b = blockIdx.y, g = blockIdx.x;
  __shared__ unsigned int hist[K*NB];           // pos<<16 | cnt, 32 KiB
  __shared__ float4 finL[K];
  __shared__ float  vlocL[K];
  for (int i = threadIdx.x*4; i < K*NB; i += 1024*4)
    *(uint4*)&hist[i] = make_uint4(0u,0u,0u,0u);
  const int wv = threadIdx.x >> 6, lane = threadIdx.x & 63;
  // ---- fused k2: wave wv (0..7) reduces spart for k=wv ----
  if (wv < K) {
    const float* p = ws + OFF_SPART + (size_t)(b*K + wv)*NBLK1*8;
    const float4 q0 = *(const float4*)(p + (size_t)lane*8);
    const float  e0 = p[(size_t)lane*8 + 4];
    const float4 q1 = *(const float4*)(p + (size_t)(lane+64)*8);
    const float  e1 = p[(size_t)(lane+64)*8 + 4];
    float a0=q0.x+q1.x, a1=q0.y+q1.y, a2=q0.z+q1.z, a3=q0.w+q1.w, a4=e0+e1;
    #pragma unroll
    for (int o=1;o<64;o<<=1){
      a0+=__shfl_xor(a0,o,64); a1+=__shfl_xor(a1,o,64); a2+=__shfl_xor(a2,o,64);
      a3+=__shfl_xor(a3,o,64); a4+=__shfl_xor(a4,o,64);
    }
    if (lane == 0) {
      const float cnt=a0, sx=a1, sy=a2, ss=a3, ss2=a4;
      const float present = (cnt > 0.0f) ? 1.0f : 0.0f;
      const float safe = fmaxf(cnt, 1.0f);
      const float cx = sx/safe, cy = sy/safe, sm = ss/safe;
      const float var = (ss2 - 2.0f*sm*ss + sm*sm*cnt)/safe;   // N_SIGMA=1
      const float sexp = expf(10.0f * sm);
      const float L2E = 1.4426950408889634f;
      finL[wv] = make_float4(-sexp*L2E,                        // a
                              2.0f*sexp*cx*L2E,                // bx
                              2.0f*sexp*cy*L2E,                // by
                             -sexp*(cx*cx + cy*cy)*L2E + 10.0f); // d0 (+10 = x1024 scale)
      vlocL[wv] = present * 10.0f * var * (1.0f/3.0f);         // W_VAR=10, /(B-1)
      if (g == 0) ws[OFF_FIN + (b*K + wv)*8 + 4] = cnt;        // for k4b
    }
  }
  __syncthreads();
  float4 fr[K];
  #pragma unroll
  for (int k=0;k<K;k++) fr[k] = finL[k];      // broadcast reads
  const float4* p0 = (const float4*)(pred + (size_t)(8*b+1)*HW);
  const float4* p1 = (const float4*)(pred + (size_t)(8*b+3)*HW);
  const float4* p3 = (const float4*)(pred + (size_t)(8*b+7)*HW);
  const int4*   in4 = (const int4*)(inst + (size_t)(2*b+1)*HW);
  float sAcc = 0.0f;
  constexpr int CH4 = HW / (G*4);
  const int base4 = g * CH4;
  for (int q0 = 0; q0 < CH4; q0 += 1024) {
    const int idx = base4 + q0 + threadIdx.x;
    const int4   iv = in4[idx];
    const float4 f0 = p0[idx];
    const float4 f1 = p1[idx];
    const float4 f3 = p3[idx];
    const int p = idx * 4;
    const float xm0 = (float)(p & (WID-1)) * (2.0f/2047.0f);
    const float ym  = (float)(p >> 10)     * (1.0f/1023.0f);
    const int ivv[4] = {iv.x, iv.y, iv.z, iv.w};
    float pxv[4], pyv[4], t2v[4], down[4];
    {
      const float a0v[4] = {f0.x, f0.y, f0.z, f0.w};
      const float a1v[4] = {f1.x, f1.y, f1.z, f1.w};
      #pragma unroll
      for (int e=0;e<4;e++){
        pxv[e] = ftanh(a0v[e]) + xm0 + (float)e*(2.0f/2047.0f);
        pyv[e] = ftanh(a1v[e]) + ym;
        t2v[e] = pxv[e]*pxv[e] + pyv[e]*pyv[e];
        down[e] = 0.0f;
      }
    }
    #pragma unroll
    for (int j=0;j<K;j++){
      const float4 f = fr[j];
      int buv[4]; unsigned addv[4];
      #pragma unroll
      for (int e=0;e<4;e++){
        const float u = fmaf(f.x, t2v[e], fmaf(f.y, pxv[e], fmaf(f.z, pyv[e], f.w)));
        const float v = fexp2(u);                 // 1024*dist in [0,1024]
        int vi = (int)v; vi = (vi > NB-1) ? NB-1 : vi;
        const bool own = (ivv[e] == j+1);
        if (own) down[e] = v;
        buv[e] = own ? (NB-1 - vi) : vi;
        addv[e] = own ? 0x10001u : 1u;
      }
      // merge runs of equal buckets within the quad (intra-thread)
      int cur = buv[0]; unsigned acc = addv[0];
      #pragma unroll
      for (int e=1;e<4;e++){
        const bool same = (buv[e] == cur);
        if (!same) atomicAdd(&hist[j*NB + cur], acc);
        acc = same ? acc + addv[e] : addv[e];
        cur = buv[e];
      }
      // cross-lane opportunistic merge within 4-lane quads (DPP, VALU-only):
      // equal-bucket lanes combine; zeroed lanes skip the atomic.
      {
        const int      nb1 = dpp_xor1_i(cur);
        const unsigned na1 = (unsigned)dpp_xor1_i((int)acc);
        if (nb1 == cur) acc = (lane & 1) ? 0u : acc + na1;
        const int      nb2 = dpp_xor2_i(cur);
        const unsigned na2 = (unsigned)dpp_xor2_i((int)acc);
        if (nb2 == cur) acc = (lane & 2) ? 0u : acc + na2;
      }
      if (acc) atomicAdd(&hist[j*NB + cur], acc);
    }
    {
      const float sdv[4] = {fsigmoid(f3.x), fsigmoid(f3.y), fsigmoid(f3.z), fsigmoid(f3.w)};
      #pragma unroll
      for (int e=0;e<4;e++){
        const float d  = (ivv[e] == 0) ? 0.0f : down[e] * (1.0f/1024.0f);
        const float df = sdv[e] - d;
        sAcc += df*df;                            // bg: sd^2; fg: (sd-dist)^2
      }
    }
  }
  __syncthreads();
  unsigned int* dst = part + ((size_t)b*G + g)*(K*NB);
  for (int i = threadIdx.x*4; i < K*NB; i += 1024*4)
    *(uint4*)&dst[i] = *(const uint4*)&hist[i];
  #pragma unroll
  for (int o=1;o<64;o<<=1) sAcc += __shfl_xor(sAcc, o, 64);
  __shared__ float wsum[16];
  if (lane == 0) wsum[wv] = sAcc;
  __syncthreads();
  if (threadIdx.x == 0) {
    float tot = 0.f;
    #pragma unroll
    for (int w = 0; w < 16; w++) tot += wsum[w];
    float add = tot * (1.0f/((float)HW * 3.0f));  // W_SEED /npix /(B-1)
    if (g == 0) {
      #pragma unroll
      for (int k = 0; k < K; k++) add += vlocL[k];  // var loss, once per image
    }
    atomicAdd(ws + OFF_LOSS, add);
  }
}

// ---------------- Kernel 4a: parallel G-way partial reduction (plain stores) ----------------
__global__ __launch_bounds__(128) void k4a_reduce(const unsigned int* __restrict__ part,
                                                  unsigned int* __restrict__ red, int G_) {
  const int bk = blockIdx.x, c = blockIdx.y;
  const int b = bk >> 3, k = bk & 7;
  const int bu = c*128 + threadIdx.x;
  const unsigned int* base = part + (size_t)b*G_*(K*NB) + (size_t)k*NB + bu;
  unsigned int rc = 0, rp = 0;
  #pragma unroll 8
  for (int g = 0; g < G_; g++) {
    const unsigned int v = base[(size_t)g*(K*NB)];
    rc += v & 0xFFFFu;
    rp += v >> 16;
  }
  red[bk*NB + bu]            = rc;
  red[B*K*NB + bk*NB + bu]   = rp;
}

// ---------------- Kernel 4b: Lovász from reduced histogram + final output ----------------
__global__ __launch_bounds__(256) void k4b_lovasz(const unsigned int* __restrict__ red,
                                                   float* __restrict__ ws,
                                                   float* __restrict__ out) {
  const int bk = blockIdx.x;                    // b*K + k
  const float cntF = ws[OFF_FIN + bk*8 + 4];
  const int t = threadIdx.x;
  if (cntF > 0.0f) {
    const double Pd = (double)cntF;
    const int lane = t & 63, wv = t >> 6;
    unsigned int cnt[4], pos[4];
    #pragma unroll
    for (int j = 0; j < 4; j++) {
      const int bu = NB-1 - (t*4 + j);            // descending error order
      cnt[j] = red[bk*NB + bu];
      pos[j] = red[B*K*NB + bk*NB + bu];
    }
    const int lc = (int)(cnt[0]+cnt[1]+cnt[2]+cnt[3]);
    const int lp = (int)(pos[0]+pos[1]+pos[2]+pos[3]);
    int ic = lc, ip = lp;
    #pragma unroll
    for (int o=1;o<64;o<<=1){
      const int vc = __shfl_up(ic, o, 64);
      const int vp = __shfl_up(ip, o, 64);
      if (lane >= o) { ic += vc; ip += vp; }
    }
    __shared__ int wtc[4], wtp[4];
    if (lane == 63) { wtc[wv] = ic; wtp[wv] = ip; }
    __syncthreads();
    int offc = 0, offp = 0;
    for (int w = 0; w < wv; w++) { offc += wtc[w]; offp += wtp[w]; }
    int irun = offc + ic - lc;                    // exclusive prefixes
    int crun = offp + ip - lp;
    double acc = 0.0;
    #pragma unroll
    for (int j = 0; j < 4; j++) {
      const int n = (int)cnt[j];
      if (n) {
        const int bu = NB-1 - (t*4 + j);
        const double jac0 = (irun==0) ? 0.0 : 1.0 - (Pd - crun)/(Pd + irun - crun);
        irun += n; crun += (int)pos[j];
        const double jac1 = 1.0 - (Pd - crun)/(Pd + irun - crun);
        acc += ((bu + 0.5) * (2.0/NB)) * (jac1 - jac0);
      }
    }
    #pragma unroll
    for (int o=1;o<64;o<<=1) acc += __shfl_xor(acc, o, 64);
    __shared__ double racc[4];
    if (lane == 0) racc[wv] = acc;
    __syncthreads();
    if (t == 0) {
      const double tot = racc[0]+racc[1]+racc[2]+racc[3];
      atomicAdd(ws + OFF_LOSS, (float)(tot * (1.0/3.0)));   // W_INST=1, /(B-1)
    }
  }
  // completion ticket: last block writes the output
  if (t == 0) {
    __threadfence();
    unsigned int* wsu = (unsigned int*)ws;
    const unsigned int old = atomicAdd(&wsu[OFF_TICK], 1u);
    if (old == (unsigned)(B*K - 1)) {
      __threadfence();
      out[0] = *((volatile float*)(ws + OFF_LOSS));
    }
  }
}

extern "C" void kernel_launch(void* const* d_in, const int* in_sizes, int n_in,
                              void* d_out, int out_size, void* d_ws, size_t ws_size,
                              hipStream_t stream) {
  const float* pred = (const float*)d_in[0];
  const int*   inst = (const int*)d_in[1];
  float* ws  = (float*)d_ws;
  float* out = (float*)d_out;
  unsigned int* red  = ((unsigned int*)d_ws) + OFF_RED;
  unsigned int* part = ((unsigned int*)d_ws) + OFF_PART;
  int G = 128;
  while (G > 32 && ws_size < ((size_t)OFF_PART + (size_t)B*G*K*NB)*4) G >>= 1;
  k1_stats<<<dim3(NBLK1,B), 512, 0, stream>>>(pred, inst, ws);
  if      (G == 128) k3_main<128><<<dim3(128,B), 1024, 0, stream>>>(pred, inst, ws, part);
  else if (G ==  64) k3_main< 64><<<dim3( 64,B), 1024, 0, stream>>>(pred, inst, ws, part);
  else               k3_main< 32><<<dim3( 32,B), 1024, 0, stream>>>(pred, inst, ws, part);
  k4a_reduce<<<dim3(B*K, 8), 128, 0, stream>>>(part, red, G);
  k4b_lovasz<<<B*K, 256, 0, stream>>>(red, ws, out);
}

// Round 10
// 133.712 us; speedup vs baseline: 1.1004x; 1.0072x over previous
//
#include <hip/hip_runtime.h>

#define H 512
#define WID 1024
#define HW (H*WID)
#define B 4
#define K 8
#define NB 1024
#define NBLK1 128                          // k1 blocks per image

// ws word (4-byte) layout
#define OFF_LOSS  0
#define OFF_TICK  1                        // out-write ticket (u32)
#define OFF_FIN   64                       // B*K*8 floats: only [+4]=cnt used
#define OFF_SPART 512                      // B*K*NBLK1*8 floats (stride 8)
#define OFF_RED   (OFF_SPART + B*K*NBLK1*8)   // 2*B*K*NB u32 (cnt then pos)
#define OFF_PART  (OFF_RED + 2*B*K*NB)     // B*G*K*NB packed u32 (pos<<16|cnt)

static __device__ __forceinline__ float frcp(float x){
#if __has_builtin(__builtin_amdgcn_rcpf)
  return __builtin_amdgcn_rcpf(x);
#else
  return 1.0f / x;
#endif
}
static __device__ __forceinline__ float fexp2(float x){
#if __has_builtin(__builtin_amdgcn_exp2f)
  return __builtin_amdgcn_exp2f(x);
#else
  return exp2f(x);
#endif
}
static __device__ __forceinline__ float ftanh(float x){
  return 1.0f - 2.0f * frcp(__expf(2.0f*x) + 1.0f);
}
static __device__ __forceinline__ float fsigmoid(float x){
  return frcp(1.0f + __expf(-x));
}
// LDS histogram add: no-return, workgroup scope, relaxed — lets the compiler
// emit fire-and-forget ds_add (no rtn, no lgkmcnt dependency on the result).
static __device__ __forceinline__ void lds_add(unsigned int* p, unsigned int v){
#if defined(__HIP_MEMORY_SCOPE_WORKGROUP)
  (void)__hip_atomic_fetch_add(p, v, __ATOMIC_RELAXED, __HIP_MEMORY_SCOPE_WORKGROUP);
#else
  atomicAdd(p, v);
#endif
}

// ---------------- Kernel 1: per-(b,k) stats + zero LOSS/TICK ----------------
__global__ __launch_bounds__(512) void k1_stats(const float* __restrict__ pred,
                                                const int* __restrict__ inst,
                                                float* __restrict__ ws) {
  const int b = blockIdx.y;
  __shared__ int4   ti[1024];
  __shared__ float4 ts[1024];
  __shared__ float  part5[K][5];
  if (b == 0 && blockIdx.x == 0) {
    if (threadIdx.x == 0) ws[OFF_LOSS] = 0.0f;
    if (threadIdx.x == 1) ((unsigned int*)ws)[OFF_TICK] = 0u;
  }
  const float4* sig4 = (const float4*)(pred + (size_t)(8*b + 5) * HW);  // ch2 t=1
  const int4*   ins4 = (const int4*)(inst + (size_t)(2*b + 1) * HW);
  const int base4 = blockIdx.x * 1024;     // 1024 int4-groups per block
  #pragma unroll
  for (int i = 0; i < 2; i++) {
    const int q = threadIdx.x + i*512;
    ti[q] = ins4[base4 + q];
    ts[q] = sig4[base4 + q];
  }
  __syncthreads();
  const int wv = threadIdx.x >> 6, lane = threadIdx.x & 63;
  const int kk = wv + 1;
  float cnt=0.f, sx=0.f, sy=0.f, ss=0.f, ss2=0.f;
  #pragma unroll
  for (int j = 0; j < 16; j++) {
    const int q = lane + 64*j;
    const int4   iv = ti[q];
    const float4 sv = ts[q];
    const int p = (base4 + q) * 4;
    const float xm0 = (float)(p & (WID-1)) * (2.0f/2047.0f);
    const float ym  = (float)(p >> 10)     * (1.0f/1023.0f);
    const float m0 = (iv.x==kk)?1.f:0.f, m1=(iv.y==kk)?1.f:0.f,
                m2 = (iv.z==kk)?1.f:0.f, m3=(iv.w==kk)?1.f:0.f;
    const float msum = (m0+m1)+(m2+m3);
    cnt += msum;
    sx  += msum*xm0 + (m1 + 2.0f*m2 + 3.0f*m3)*(2.0f/2047.0f);
    sy  += msum*ym;
    ss  += m0*sv.x + m1*sv.y + m2*sv.z + m3*sv.w;
    ss2 += m0*sv.x*sv.x + m1*sv.y*sv.y + m2*sv.z*sv.z + m3*sv.w*sv.w;
  }
  #pragma unroll
  for (int o=1;o<64;o<<=1){
    cnt+=__shfl_xor(cnt,o,64);
    sx +=__shfl_xor(sx, o,64);
    sy +=__shfl_xor(sy, o,64);
    ss +=__shfl_xor(ss, o,64);
    ss2+=__shfl_xor(ss2,o,64);
  }
  if (lane == 0) {
    part5[wv][0]=cnt; part5[wv][1]=sx; part5[wv][2]=sy; part5[wv][3]=ss; part5[wv][4]=ss2;
  }
  __syncthreads();
  if (threadIdx.x < K*8) {
    const int w = threadIdx.x >> 3, c = threadIdx.x & 7;
    if (c < 5)
      ws[OFF_SPART + ((size_t)(b*K + w)*NBLK1 + blockIdx.x)*8 + c] = part5[w][c];
  }
}

// ---------------- Kernel 3: main pass (k2 fused) — branchless fire-and-forget atomics ----------------
// 1024 thr (16 waves), G=128 -> 2 blocks/CU = 32 waves/CU. Buckets are RANDOM
// (pred is N(0,1) noise) so all merge schemes were dead weight (r9 null) —
// removed. Hist adds are straight-line ds_add, no-return workgroup-relaxed,
// zero branches around them. Flush stays plain coalesced uint4 stores
// (cross-block atomics cost 15-25 µs — rounds 6/7/8).
template<int G>
__global__ __launch_bounds__(1024, 8) void k3_main(const float* __restrict__ pred,
                                                   const int* __restrict__ inst,
                                                   float* __restrict__ ws,
                                                   unsigned int* __restrict__ part) {
  const int b = blockIdx.y, g = blockIdx.x;
  __shared__ unsigned int hist[K*NB];           // pos<<16 | cnt, 32 KiB
  __shared__ float4 finL[K];
  __shared__ float  vlocL[K];
  for (int i = threadIdx.x*4; i < K*NB; i += 1024*4)
    *(uint4*)&hist[i] = make_uint4(0u,0u,0u,0u);
  const int wv = threadIdx.x >> 6, lane = threadIdx.x & 63;
  // ---- fused k2: wave wv (0..7) reduces spart for k=wv ----
  if (wv < K) {
    const float* p = ws + OFF_SPART + (size_t)(b*K + wv)*NBLK1*8;
    const float4 q0 = *(const float4*)(p + (size_t)lane*8);
    const float  e0 = p[(size_t)lane*8 + 4];
    const float4 q1 = *(const float4*)(p + (size_t)(lane+64)*8);
    const float  e1 = p[(size_t)(lane+64)*8 + 4];
    float a0=q0.x+q1.x, a1=q0.y+q1.y, a2=q0.z+q1.z, a3=q0.w+q1.w, a4=e0+e1;
    #pragma unroll
    for (int o=1;o<64;o<<=1){
      a0+=__shfl_xor(a0,o,64); a1+=__shfl_xor(a1,o,64); a2+=__shfl_xor(a2,o,64);
      a3+=__shfl_xor(a3,o,64); a4+=__shfl_xor(a4,o,64);
    }
    if (lane == 0) {
      const float cnt=a0, sx=a1, sy=a2, ss=a3, ss2=a4;
      const float present = (cnt > 0.0f) ? 1.0f : 0.0f;
      const float safe = fmaxf(cnt, 1.0f);
      const float cx = sx/safe, cy = sy/safe, sm = ss/safe;
      const float var = (ss2 - 2.0f*sm*ss + sm*sm*cnt)/safe;   // N_SIGMA=1
      const float sexp = expf(10.0f * sm);
      const float L2E = 1.4426950408889634f;
      finL[wv] = make_float4(-sexp*L2E,                        // a
                              2.0f*sexp*cx*L2E,                // bx
                              2.0f*sexp*cy*L2E,                // by
                             -sexp*(cx*cx + cy*cy)*L2E + 10.0f); // d0 (+10 = x1024 scale)
      vlocL[wv] = present * 10.0f * var * (1.0f/3.0f);         // W_VAR=10, /(B-1)
      if (g == 0) ws[OFF_FIN + (b*K + wv)*8 + 4] = cnt;        // for k4b
    }
  }
  __syncthreads();
  float4 fr[K];
  #pragma unroll
  for (int k=0;k<K;k++) fr[k] = finL[k];      // broadcast reads
  const float4* p0 = (const float4*)(pred + (size_t)(8*b+1)*HW);
  const float4* p1 = (const float4*)(pred + (size_t)(8*b+3)*HW);
  const float4* p3 = (const float4*)(pred + (size_t)(8*b+7)*HW);
  const int4*   in4 = (const int4*)(inst + (size_t)(2*b+1)*HW);
  float sAcc = 0.0f;
  constexpr int CH4 = HW / (G*4);
  const int base4 = g * CH4;
  for (int q0 = 0; q0 < CH4; q0 += 1024) {
    const int idx = base4 + q0 + threadIdx.x;
    const int4   iv = in4[idx];
    const float4 f0 = p0[idx];
    const float4 f1 = p1[idx];
    const float4 f3 = p3[idx];
    const int p = idx * 4;
    const float xm0 = (float)(p & (WID-1)) * (2.0f/2047.0f);
    const float ym  = (float)(p >> 10)     * (1.0f/1023.0f);
    const int ivv[4] = {iv.x, iv.y, iv.z, iv.w};
    float pxv[4], pyv[4], t2v[4], down[4];
    {
      const float a0v[4] = {f0.x, f0.y, f0.z, f0.w};
      const float a1v[4] = {f1.x, f1.y, f1.z, f1.w};
      #pragma unroll
      for (int e=0;e<4;e++){
        pxv[e] = ftanh(a0v[e]) + xm0 + (float)e*(2.0f/2047.0f);
        pyv[e] = ftanh(a1v[e]) + ym;
        t2v[e] = pxv[e]*pxv[e] + pyv[e]*pyv[e];
        down[e] = 0.0f;
      }
    }
    #pragma unroll
    for (int j=0;j<K;j++){
      const float4 f = fr[j];
      #pragma unroll
      for (int e=0;e<4;e++){
        const float u = fmaf(f.x, t2v[e], fmaf(f.y, pxv[e], fmaf(f.z, pyv[e], f.w)));
        const float v = fexp2(u);                 // 1024*dist in [0,1024]
        int vi = (int)v; vi = (vi > NB-1) ? NB-1 : vi;
        const bool own = (ivv[e] == j+1);
        if (own) down[e] = v;
        const int bu = own ? (NB-1 - vi) : vi;
        const unsigned add = own ? 0x10001u : 1u;
        lds_add(&hist[j*NB + bu], add);           // branchless fire-and-forget
      }
    }
    {
      const float sdv[4] = {fsigmoid(f3.x), fsigmoid(f3.y), fsigmoid(f3.z), fsigmoid(f3.w)};
      #pragma unroll
      for (int e=0;e<4;e++){
        const float d  = (ivv[e] == 0) ? 0.0f : down[e] * (1.0f/1024.0f);
        const float df = sdv[e] - d;
        sAcc += df*df;                            // bg: sd^2; fg: (sd-dist)^2
      }
    }
  }
  __syncthreads();
  unsigned int* dst = part + ((size_t)b*G + g)*(K*NB);
  for (int i = threadIdx.x*4; i < K*NB; i += 1024*4)
    *(uint4*)&dst[i] = *(const uint4*)&hist[i];
  #pragma unroll
  for (int o=1;o<64;o<<=1) sAcc += __shfl_xor(sAcc, o, 64);
  __shared__ float wsum[16];
  if (lane == 0) wsum[wv] = sAcc;
  __syncthreads();
  if (threadIdx.x == 0) {
    float tot = 0.f;
    #pragma unroll
    for (int w = 0; w < 16; w++) tot += wsum[w];
    float add = tot * (1.0f/((float)HW * 3.0f));  // W_SEED /npix /(B-1)
    if (g == 0) {
      #pragma unroll
      for (int k = 0; k < K; k++) add += vlocL[k];  // var loss, once per image
    }
    atomicAdd(ws + OFF_LOSS, add);
  }
}

// ---------------- Kernel 4a: parallel G-way partial reduction (plain stores) ----------------
__global__ __launch_bounds__(128) void k4a_reduce(const unsigned int* __restrict__ part,
                                                  unsigned int* __restrict__ red, int G_) {
  const int bk = blockIdx.x, c = blockIdx.y;
  const int b = bk >> 3, k = bk & 7;
  const int bu = c*128 + threadIdx.x;
  const unsigned int* base = part + (size_t)b*G_*(K*NB) + (size_t)k*NB + bu;
  unsigned int rc = 0, rp = 0;
  #pragma unroll 8
  for (int g = 0; g < G_; g++) {
    const unsigned int v = base[(size_t)g*(K*NB)];
    rc += v & 0xFFFFu;
    rp += v >> 16;
  }
  red[bk*NB + bu]            = rc;
  red[B*K*NB + bk*NB + bu]   = rp;
}

// ---------------- Kernel 4b: Lovász from reduced histogram + final output ----------------
__global__ __launch_bounds__(256) void k4b_lovasz(const unsigned int* __restrict__ red,
                                                   float* __restrict__ ws,
                                                   float* __restrict__ out) {
  const int bk = blockIdx.x;                    // b*K + k
  const float cntF = ws[OFF_FIN + bk*8 + 4];
  const int t = threadIdx.x;
  if (cntF > 0.0f) {
    const double Pd = (double)cntF;
    const int lane = t & 63, wv = t >> 6;
    unsigned int cnt[4], pos[4];
    #pragma unroll
    for (int j = 0; j < 4; j++) {
      const int bu = NB-1 - (t*4 + j);            // descending error order
      cnt[j] = red[bk*NB + bu];
      pos[j] = red[B*K*NB + bk*NB + bu];
    }
    const int lc = (int)(cnt[0]+cnt[1]+cnt[2]+cnt[3]);
    const int lp = (int)(pos[0]+pos[1]+pos[2]+pos[3]);
    int ic = lc, ip = lp;
    #pragma unroll
    for (int o=1;o<64;o<<=1){
      const int vc = __shfl_up(ic, o, 64);
      const int vp = __shfl_up(ip, o, 64);
      if (lane >= o) { ic += vc; ip += vp; }
    }
    __shared__ int wtc[4], wtp[4];
    if (lane == 63) { wtc[wv] = ic; wtp[wv] = ip; }
    __syncthreads();
    int offc = 0, offp = 0;
    for (int w = 0; w < wv; w++) { offc += wtc[w]; offp += wtp[w]; }
    int irun = offc + ic - lc;                    // exclusive prefixes
    int crun = offp + ip - lp;
    double acc = 0.0;
    #pragma unroll
    for (int j = 0; j < 4; j++) {
      const int n = (int)cnt[j];
      if (n) {
        const int bu = NB-1 - (t*4 + j);
        const double jac0 = (irun==0) ? 0.0 : 1.0 - (Pd - crun)/(Pd + irun - crun);
        irun += n; crun += (int)pos[j];
        const double jac1 = 1.0 - (Pd - crun)/(Pd + irun - crun);
        acc += ((bu + 0.5) * (2.0/NB)) * (jac1 - jac0);
      }
    }
    #pragma unroll
    for (int o=1;o<64;o<<=1) acc += __shfl_xor(acc, o, 64);
    __shared__ double racc[4];
    if (lane == 0) racc[wv] = acc;
    __syncthreads();
    if (t == 0) {
      const double tot = racc[0]+racc[1]+racc[2]+racc[3];
      atomicAdd(ws + OFF_LOSS, (float)(tot * (1.0/3.0)));   // W_INST=1, /(B-1)
    }
  }
  // completion ticket: last block writes the output
  if (t == 0) {
    __threadfence();
    unsigned int* wsu = (unsigned int*)ws;
    const unsigned int old = atomicAdd(&wsu[OFF_TICK], 1u);
    if (old == (unsigned)(B*K - 1)) {
      __threadfence();
      out[0] = *((volatile float*)(ws + OFF_LOSS));
    }
  }
}

extern "C" void kernel_launch(void* const* d_in, const int* in_sizes, int n_in,
                              void* d_out, int out_size, void* d_ws, size_t ws_size,
                              hipStream_t stream) {
  const float* pred = (const float*)d_in[0];
  const int*   inst = (const int*)d_in[1];
  float* ws  = (float*)d_ws;
  float* out = (float*)d_out;
  unsigned int* red  = ((unsigned int*)d_ws) + OFF_RED;
  unsigned int* part = ((unsigned int*)d_ws) + OFF_PART;
  int G = 128;
  while (G > 32 && ws_size < ((size_t)OFF_PART + (size_t)B*G*K*NB)*4) G >>= 1;
  k1_stats<<<dim3(NBLK1,B), 512, 0, stream>>>(pred, inst, ws);
  if      (G == 128) k3_main<128><<<dim3(128,B), 1024, 0, stream>>>(pred, inst, ws, part);
  else if (G ==  64) k3_main< 64><<<dim3( 64,B), 1024, 0, stream>>>(pred, inst, ws, part);
  else               k3_main< 32><<<dim3( 32,B), 1024, 0, stream>>>(pred, inst, ws, part);
  k4a_reduce<<<dim3(B*K, 8), 128, 0, stream>>>(part, red, G);
  k4b_lovasz<<<B*K, 256, 0, stream>>>(red, ws, out);
}